// Round 15
// baseline (1115.694 us; speedup 1.0000x reference)
//
#include <hip/hip_runtime.h>
#include <math.h>

#define NI 512
#define CC 512
#define KCL 64
#define HW49 49
#define CQ 25088   // 512*49
#define AP 260     // kCw1 A-tile pitch [q][n]
#define GP 68      // kCw1 G-tile pitch [q][p pad 64]
#define XQP 132    // kLog transposed quarter pitch (33 granules == 1 mod 32)

// Upsample matrix U[13][7], align_corners: even i -> 1 at i/2; odd i -> 0.5 at (i-1)/2,(i+1)/2
__device__ __forceinline__ float Uval(int i, int u) {
    if (i & 1) return (u == ((i - 1) >> 1) || u == ((i + 1) >> 1)) ? 0.5f : 0.0f;
    return (u == (i >> 1)) ? 1.0f : 0.0f;
}

// ---------------- K_G: build per-channel 49x49 operator (lnw folded in, lnb -> Gl) ----------------
__global__ __launch_bounds__(256) void kG(
    const float* __restrict__ c3w, const float* __restrict__ c5w, const float* __restrict__ c7w,
    const float* __restrict__ dww, const float* __restrict__ dhw, const float* __restrict__ accw,
    const float* __restrict__ lnw, const float* __restrict__ lnb,
    float* __restrict__ Gmat, float* __restrict__ Gl)
{
    const int c = blockIdx.x;
    const int t = threadIdx.x;
    __shared__ float dh[91], dw[91];
    __shared__ float Fh3[147], Fw3[147], Fh5[245], Fw5[245], Fh7[343], Fw7[343];
    __shared__ float wa3[9], wa5[25], wa7[49];
    __shared__ float Gtmp[2401];
    if (t < 91) dh[t] = dhw[t];
    if (t >= 128 && t < 219) dw[t - 128] = dww[t - 128];
    __syncthreads();
    for (int idx = t; idx < 147; idx += 256) {
        int oh = idx / 21, r = idx % 21, u = r / 3, dy = r % 3;
        float sh = 0.f, sw = 0.f;
        for (int i = 0; i < 13; i++) { int y = i - dy + 1; if (y >= 0 && y < 13) { float uu = Uval(i, u); sh += dh[oh * 13 + y] * uu; sw += dw[oh * 13 + y] * uu; } }
        Fh3[idx] = sh; Fw3[idx] = sw;
    }
    for (int idx = t; idx < 245; idx += 256) {
        int oh = idx / 35, r = idx % 35, u = r / 5, dy = r % 5;
        float sh = 0.f, sw = 0.f;
        for (int i = 0; i < 13; i++) { int y = i - dy + 2; if (y >= 0 && y < 13) { float uu = Uval(i, u); sh += dh[oh * 13 + y] * uu; sw += dw[oh * 13 + y] * uu; } }
        Fh5[idx] = sh; Fw5[idx] = sw;
    }
    for (int idx = t; idx < 343; idx += 256) {
        int oh = idx / 49, r = idx % 49, u = r / 7, dy = r % 7;
        float sh = 0.f, sw = 0.f;
        for (int i = 0; i < 13; i++) { int y = i - dy + 3; if (y >= 0 && y < 13) { float uu = Uval(i, u); sh += dh[oh * 13 + y] * uu; sw += dw[oh * 13 + y] * uu; } }
        Fh7[idx] = sh; Fw7[idx] = sw;
    }
    if (t < 9)               { float s = 0.f; for (int co = 0; co < 32; co++) s += accw[co]      * c3w[(size_t)(co * 512 + c) * 9  + t];        wa3[t] = s; }
    if (t >= 32 && t < 57)   { int q = t - 32; float s = 0.f; for (int co = 0; co < 32; co++) s += accw[32 + co] * c5w[(size_t)(co * 512 + c) * 25 + q]; wa5[q] = s; }
    if (t >= 64 && t < 113)  { int q = t - 64; float s = 0.f; for (int co = 0; co < 20; co++) s += accw[64 + co] * c7w[(size_t)(co * 512 + c) * 49 + q]; wa7[q] = s; }
    __syncthreads();
    for (int o = t; o < 2401; o += 256) {
        int q = o / 49, p = o % 49;
        int u = q / 7, v = q % 7, ow = p / 7, oh = p % 7;
        float acc = 0.f;
        #pragma unroll
        for (int dy = 0; dy < 3; dy++) { float fh = Fh3[(oh * 7 + u) * 3 + dy];
            #pragma unroll
            for (int dx = 0; dx < 3; dx++) acc += wa3[dy * 3 + dx] * fh * Fw3[(ow * 7 + v) * 3 + dx]; }
        #pragma unroll
        for (int dy = 0; dy < 5; dy++) { float fh = Fh5[(oh * 7 + u) * 5 + dy];
            #pragma unroll
            for (int dx = 0; dx < 5; dx++) acc += wa5[dy * 5 + dx] * fh * Fw5[(ow * 7 + v) * 5 + dx]; }
        #pragma unroll
        for (int dy = 0; dy < 7; dy++) { float fh = Fh7[(oh * 7 + u) * 7 + dy];
            #pragma unroll
            for (int dx = 0; dx < 7; dx++) acc += wa7[dy * 7 + dx] * fh * Fw7[(ow * 7 + v) * 7 + dx]; }
        Gtmp[o] = acc;
        Gmat[(size_t)c * 2401 + o] = acc * lnw[q];
    }
    __syncthreads();
    if (t < 49) {
        float s = 0.f;
        for (int q = 0; q < 49; q++) s += Gtmp[q * 49 + t] * lnb[q];
        Gl[c * 49 + t] = s;
    }
}

// ---------------- K_Cb: constant term of cw (incl. lnb fold via Gl) ----------------
__global__ void kCb(const float* __restrict__ c3b, const float* __restrict__ c5b, const float* __restrict__ c7b,
                    const float* __restrict__ dww, const float* __restrict__ dwb,
                    const float* __restrict__ dhw, const float* __restrict__ dhb,
                    const float* __restrict__ accw, const float* __restrict__ accb,
                    const float* __restrict__ Gl, float* __restrict__ Cb)
{
    __shared__ float A0s, A1s, Sdw[7], Sdh[7];
    int t = threadIdx.x;
    if (t == 0) {
        float a0 = 0.f, a1 = 0.f;
        for (int co = 0; co < 84; co++) {
            float aw = accw[co]; a0 += aw;
            float b = (co < 32) ? c3b[co] : ((co < 64) ? c5b[co - 32] : c7b[co - 64]);
            a1 += aw * b;
        }
        A0s = a0; A1s = a1;
    }
    if (t < 7)             { float s = 0.f; for (int xx = 0; xx < 13; xx++) s += dww[t * 13 + xx]; Sdw[t] = s; }
    if (t >= 8 && t < 15)  { int oh = t - 8; float s = 0.f; for (int y = 0; y < 13; y++) s += dhw[oh * 13 + y]; Sdh[oh] = s; }
    __syncthreads();
    if (t < 49) {
        int ow = t / 7, oh = t % 7;
        float g = 0.f;
        for (int c = 0; c < 512; c++) g += Gl[c * 49 + t];
        Cb[t] = A1s * Sdw[ow] * Sdh[oh] + A0s * (dwb[ow] * Sdh[oh] + dhb[oh]) + accb[0] + g;
    }
}

// ---------------- K_cw1: partial GEMM with inline LayerNorm (512 threads, 16 waves/CU) ----------------
__global__ __launch_bounds__(512) void kCw1(const float* __restrict__ x,
    const float* __restrict__ Gmat, float* __restrict__ part)
{
    __shared__ float As[49 * AP];   // [q][n]; reused as [256][49] out-stage
    __shared__ float Gs[49 * GP];   // [q][p pad 64]
    const int b = blockIdx.x;
    const int nt = b >> 8, ks = b & 255;
    const int n0 = nt * 256;
    const int t = threadIdx.x;
    const int tn = t >> 3;          // 0..63 -> rows 4*tn..4*tn+3
    const int tp = t & 7;           // p-octet
    float acc[4][8];
    #pragma unroll
    for (int j = 0; j < 4; j++)
        #pragma unroll
        for (int m = 0; m < 8; m++) acc[j][m] = 0.f;
    for (int kk = 0; kk < 2; kk++) {
        const int c = ks * 2 + kk;
        for (int i = t; i < 12544; i += 512) {
            int nr = i / 49, q = i - nr * 49;
            As[q * AP + nr] = x[(size_t)(n0 + nr) * CQ + (size_t)c * 49 + q];
        }
        for (int i = t; i < 2401; i += 512) {
            int q = i / 49, p = i - q * 49;
            Gs[q * GP + p] = Gmat[(size_t)c * 2401 + i];
        }
        for (int i = t; i < 735; i += 512) {
            int q = i / 15, pc = 49 + (i - q * 15);
            Gs[q * GP + pc] = 0.f;
        }
        __syncthreads();
        if (t < 256) {
            float s = 0.f, ss = 0.f;
            for (int q = 0; q < 49; q++) { float v = As[q * AP + t]; s += v; ss += v * v; }
            float mu = s * (1.f / 49.f);
            float var = ss * (1.f / 49.f) - mu * mu;
            float rs = 1.f / sqrtf(var + 1e-5f);
            for (int q = 0; q < 49; q++) As[q * AP + t] = (As[q * AP + t] - mu) * rs;
        }
        __syncthreads();
        for (int q = 0; q < 49; q++) {
            float4 a0 = *(const float4*)&As[q * AP + tn * 4];
            float4 g0 = *(const float4*)&Gs[q * GP + tp * 8];
            float4 g1 = *(const float4*)&Gs[q * GP + tp * 8 + 4];
            float av[4] = {a0.x, a0.y, a0.z, a0.w};
            float gv[8] = {g0.x, g0.y, g0.z, g0.w, g1.x, g1.y, g1.z, g1.w};
            #pragma unroll
            for (int j = 0; j < 4; j++)
                #pragma unroll
                for (int m = 0; m < 8; m++) acc[j][m] += av[j] * gv[m];
        }
        __syncthreads();
    }
    #pragma unroll
    for (int j = 0; j < 4; j++) {
        #pragma unroll
        for (int m = 0; m < 8; m++) {
            int p = tp * 8 + m;
            if (p < 49) As[(tn * 4 + j) * 49 + p] = acc[j][m];
        }
    }
    __syncthreads();
    {
        float* dst = part + (size_t)ks * CQ + (size_t)n0 * 49;
        for (int i = t; i < 12544; i += 512) dst[i] = As[i];
    }
}

// ---------------- K_log: cw-reduce + rn + logits + softmax -> maskr (sa*cw*rn), msum ----------------
// Double-buffered transposed x staging, s_load weights, coalesced cw-reduce.
__global__ __launch_bounds__(512) void kLog(const float* __restrict__ x,
    const float* __restrict__ convw, const float* __restrict__ convb,
    const float* __restrict__ part, const float* __restrict__ Cbg,
    float* __restrict__ maskr, float* __restrict__ msum)
{
    __shared__ float xq[2][49 * XQP];   // double-buffered quarter [49 l][132]
    __shared__ float lg[64 * 52];
    __shared__ float ps[8 * 56];
    __shared__ float rn[49], cwl[49], smax[49], sinv[49];
    __shared__ float cb[64];
    __shared__ float pmx[392], psm[392];
    const int n = blockIdx.x;
    const int t = threadIdx.x;
    const int lane = t & 63;
    const int kw = __builtin_amdgcn_readfirstlane(t >> 6);
    const float* xp = x + (size_t)n * CQ;

    // staging slot geometry (4 slots, slot 3 valid only for t<32)
    int scg[4], sl[4];
    #pragma unroll
    for (int s = 0; s < 4; s++) {
        int idx = t + s * 512;
        scg[s] = idx / 49; sl[s] = idx - scg[s] * 49;
    }
    float4 r[4];
    // issue loads for quarter 0
    #pragma unroll
    for (int s = 0; s < 4; s++) {
        if (s < 3 || t < 32) {
            const float* src = xp + (size_t)(scg[s] * 4) * 49 + sl[s];
            r[s].x = src[0]; r[s].y = src[49]; r[s].z = src[98]; r[s].w = src[147];
        }
    }
    // coalesced cw-reduce: wave kw -> ks [kw*32, kw*32+32), lane = p
    if (lane < 49) {
        const float* bp = part + (size_t)(kw * 32) * CQ + (size_t)n * 49 + lane;
        float s0 = 0.f, s1 = 0.f, s2 = 0.f, s3 = 0.f;
        for (int i = 0; i < 32; i += 4) {
            s0 += bp[(size_t)(i + 0) * CQ];
            s1 += bp[(size_t)(i + 1) * CQ];
            s2 += bp[(size_t)(i + 2) * CQ];
            s3 += bp[(size_t)(i + 3) * CQ];
        }
        psm[lane * 8 + kw] = (s0 + s1) + (s2 + s3);
    }
    if (t < 64) cb[t] = convb[t];

    float a[8] = {0.f, 0.f, 0.f, 0.f, 0.f, 0.f, 0.f, 0.f};
    float rs_part = 0.f;

    // write quarter 0, issue loads for quarter 1
    #pragma unroll
    for (int s = 0; s < 4; s++)
        if (s < 3 || t < 32) *(float4*)&xq[0][sl[s] * XQP + scg[s] * 4] = r[s];
    #pragma unroll
    for (int s = 0; s < 4; s++) {
        if (s < 3 || t < 32) {
            const float* src = xp + (size_t)(128 + scg[s] * 4) * 49 + sl[s];
            r[s].x = src[0]; r[s].y = src[49]; r[s].z = src[98]; r[s].w = src[147];
        }
    }
    __syncthreads();
    if (t < 49) {
        float s = Cbg[t];
        #pragma unroll
        for (int q = 0; q < 8; q++) s += psm[t * 8 + q];
        cwl[t] = s;
    }
    for (int qt = 0; qt < 4; qt++) {
        const float* buf = xq[qt & 1];
        if (lane < 49) {                 // rn partial: wave covers 16 c of this quarter, b128
            const float* row = &buf[lane * XQP + kw * 16];
            #pragma unroll
            for (int c4 = 0; c4 < 4; c4++) {
                float4 v = *(const float4*)(row + c4 * 4);
                rs_part += v.x * v.x + v.y * v.y + v.z * v.z + v.w * v.w;
            }
        }
        {                                // logits partial: x b128 from LDS, w via s_load
            const int lr = (lane < 49) ? lane : 48;
            const float* xrow = &buf[lr * XQP];
            const float* wb = convw + (size_t)(kw * 8) * 512 + qt * 128;
            for (int c4 = 0; c4 < 32; c4++) {
                float4 xv = *(const float4*)(xrow + c4 * 4);
                #pragma unroll
                for (int j = 0; j < 8; j++) {
                    float4 wv = *(const float4*)&wb[j * 512 + c4 * 4];
                    a[j] += wv.x * xv.x + wv.y * xv.y + wv.z * xv.z + wv.w * xv.w;
                }
            }
        }
        if (qt < 3) {
            #pragma unroll
            for (int s = 0; s < 4; s++)
                if (s < 3 || t < 32) *(float4*)&xq[(qt + 1) & 1][sl[s] * XQP + scg[s] * 4] = r[s];
            if (qt < 2) {
                #pragma unroll
                for (int s = 0; s < 4; s++) {
                    if (s < 3 || t < 32) {
                        const float* src = xp + (size_t)((qt + 2) * 128 + scg[s] * 4) * 49 + sl[s];
                        r[s].x = src[0]; r[s].y = src[49]; r[s].z = src[98]; r[s].w = src[147];
                    }
                }
            }
            __syncthreads();
        }
    }
    if (lane < 49) ps[kw * 56 + lane] = rs_part;
    __syncthreads();
    if (t < 49) {
        float s = 0.f;
        #pragma unroll
        for (int q = 0; q < 8; q++) s += ps[q * 56 + t];
        rn[t] = 1.f / fmaxf(sqrtf(s), 1e-12f);
    }
    __syncthreads();
    if (lane < 49) {
        float r0 = rn[lane];
        #pragma unroll
        for (int j = 0; j < 8; j++) lg[(kw * 8 + j) * 52 + lane] = a[j] * r0 + cb[kw * 8 + j];
    }
    __syncthreads();
    // softmax over k per l
    if (t < 392) {
        int l = t >> 3, kq = t & 7;
        float m = -3.402823466e38f;
        #pragma unroll
        for (int j = 0; j < 8; j++) m = fmaxf(m, lg[(kq * 8 + j) * 52 + l]);
        pmx[t] = m;
    }
    __syncthreads();
    if (t < 49) {
        float m = pmx[t * 8];
        #pragma unroll
        for (int q = 1; q < 8; q++) m = fmaxf(m, pmx[t * 8 + q]);
        smax[t] = m;
    }
    __syncthreads();
    if (t < 392) {
        int l = t >> 3, kq = t & 7;
        float m = smax[l], s = 0.f;
        #pragma unroll
        for (int j = 0; j < 8; j++) s += __expf(lg[(kq * 8 + j) * 52 + l] - m);
        psm[t] = s;
    }
    __syncthreads();
    if (t < 49) {
        float s = 0.f;
        #pragma unroll
        for (int q = 0; q < 8; q++) s += psm[t * 8 + q];
        sinv[t] = 1.f / s;
    }
    __syncthreads();
    if (t < 392) {
        int l = t >> 3, kq = t & 7;
        float m = smax[l], si = sinv[l] * cwl[l];
        #pragma unroll
        for (int j = 0; j < 8; j++) {
            int idx = (kq * 8 + j) * 52 + l;
            lg[idx] = __expf(lg[idx] - m) * si;    // mask = sa*cw
        }
    }
    __syncthreads();
    // msum per wave (pre-rn), then write mask*rn
    {
        float msr[8];
        #pragma unroll
        for (int j = 0; j < 8; j++) {
            float s = 0.f;
            for (int l = 0; l < 49; l++) s += lg[(kw * 8 + j) * 52 + l];
            msr[j] = s;
        }
        if (lane == 0) {
            #pragma unroll
            for (int j = 0; j < 8; j++) msum[n * 64 + kw * 8 + j] = msr[j];
        }
    }
    for (int o = t; o < 3136; o += 512) {
        int k = o / 49, l = o - k * 49;
        maskr[(size_t)n * 3136 + o] = lg[k * 52 + l] * rn[l];
    }
}

// ---------------- K_vd: VLAD aggregation + intra-norm + global norm ----------------
// 128-c quarter tiles: LDS ~39KB -> 4 blocks/CU (32 waves, 100% occ). qt loop fully
// unrolled so acc[8][8] stays statically indexed (no scratch). No launch_bounds cap.
__global__ __launch_bounds__(512) void kVd(const float* __restrict__ x,
    const float* __restrict__ maskr, const float* __restrict__ msum,
    const float* __restrict__ cent, float* __restrict__ out)
{
    __shared__ float xh[6288];          // 128 c x 49 l native + 16 guard
    __shared__ float lg[64 * 52];       // mask (sa*cw*rn), l 49..51 padded 0
    __shared__ float ssq[64], scl[64];
    const int n = blockIdx.x;
    const int t = threadIdx.x;
    const int lane = t & 63;
    const int kw = __builtin_amdgcn_readfirstlane(t >> 6);
    const float* xp = x + (size_t)n * CQ;
    for (int i = t; i < 3136; i += 512) { int k = i / 49, l = i - k * 49; lg[k * 52 + l] = maskr[(size_t)n * 3136 + i]; }
    for (int i = t; i < 192; i += 512) { lg[(i / 3) * 52 + 49 + (i % 3)] = 0.f; }
    if (t < 16) xh[6272 + t] = 0.f;     // guard for l-overrun of last channel (persists across quarters)
    float msr[8];
    #pragma unroll
    for (int j = 0; j < 8; j++) msr[j] = msum[n * 64 + kw * 8 + j];
    float acc[8][8];
    #pragma unroll
    for (int j = 0; j < 8; j++)
        #pragma unroll
        for (int m = 0; m < 8; m++) acc[j][m] = 0.f;
    #pragma unroll
    for (int qt = 0; qt < 4; qt++) {
        __syncthreads();                // prev quarter's readers done (and lg/guard ready gate below)
        for (int i4 = t; i4 < 1568; i4 += 512)
            *(float4*)&xh[i4 * 4] = *(const float4*)&xp[qt * 6272 + i4 * 4];
        __syncthreads();                // xh (and on qt=0: lg, guard) visible
        for (int lq = 0; lq < 13; lq++) {
            float xr0[4], xr1[4];
            #pragma unroll
            for (int dl = 0; dl < 4; dl++) {
                xr0[dl] = xh[lane * 49 + lq * 4 + dl];
                xr1[dl] = xh[(lane + 64) * 49 + lq * 4 + dl];
            }
            #pragma unroll
            for (int j = 0; j < 8; j++) {
                float4 mv = *(const float4*)&lg[(kw * 8 + j) * 52 + lq * 4];
                acc[j][qt * 2 + 0] += mv.x * xr0[0] + mv.y * xr0[1] + mv.z * xr0[2] + mv.w * xr0[3];
                acc[j][qt * 2 + 1] += mv.x * xr1[0] + mv.y * xr1[1] + mv.z * xr1[2] + mv.w * xr1[3];
            }
        }
    }
    // ---- epilogue: centroid subtract, intra-norm, global norm ----
    float ssr[8];
    #pragma unroll
    for (int j = 0; j < 8; j++) {
        int k = kw * 8 + j;
        float ms = msr[j];
        float s = 0.f;
        #pragma unroll
        for (int m = 0; m < 8; m++) {
            int c = (m >> 1) * 128 + (m & 1) * 64 + lane;
            float va = acc[j][m] - cent[(size_t)k * 512 + c] * ms;
            acc[j][m] = va;
            s += va * va;
        }
        ssr[j] = s;
    }
    #pragma unroll
    for (int j = 0; j < 8; j++)
        for (int off = 32; off >= 1; off >>= 1) ssr[j] += __shfl_xor(ssr[j], off, 64);
    if (lane == 0) {
        #pragma unroll
        for (int j = 0; j < 8; j++) ssq[kw * 8 + j] = ssr[j];
    }
    __syncthreads();
    if (t < 64) {
        float nrm = sqrtf(ssq[t]);
        float inv = 1.f / fmaxf(nrm, 1e-12f);
        float sk = nrm * inv;
        float g = sk * sk;
        #pragma unroll
        for (int off = 32; off >= 1; off >>= 1) g += __shfl_xor(g, off, 64);
        scl[t] = inv * (1.f / fmaxf(sqrtf(g), 1e-12f));
    }
    __syncthreads();
    #pragma unroll
    for (int j = 0; j < 8; j++) {
        int k = kw * 8 + j;
        float s2 = scl[k];
        #pragma unroll
        for (int m = 0; m < 8; m++) {
            int c = (m >> 1) * 128 + (m & 1) * 64 + lane;
            out[(size_t)n * 32768 + (size_t)k * 512 + c] = acc[j][m] * s2;
        }
    }
}

extern "C" void kernel_launch(void* const* d_in, const int* in_sizes, int n_in,
                              void* d_out, int out_size, void* d_ws, size_t ws_size,
                              hipStream_t stream)
{
    const float* x     = (const float*)d_in[0];
    const float* cent  = (const float*)d_in[1];
    const float* convw = (const float*)d_in[2];
    const float* convb = (const float*)d_in[3];
    const float* lnw   = (const float*)d_in[4];
    const float* lnb   = (const float*)d_in[5];
    const float* c3w   = (const float*)d_in[6];
    const float* c3b   = (const float*)d_in[7];
    const float* c5w   = (const float*)d_in[8];
    const float* c5b   = (const float*)d_in[9];
    const float* c7w   = (const float*)d_in[10];
    const float* c7b   = (const float*)d_in[11];
    const float* dww   = (const float*)d_in[12];
    const float* dwb   = (const float*)d_in[13];
    const float* dhw   = (const float*)d_in[14];
    const float* dhb   = (const float*)d_in[15];
    const float* accw  = (const float*)d_in[16];
    const float* accb  = (const float*)d_in[17];
    float* out = (float*)d_out;

    char* ws = (char*)d_ws;
    float* Gmat  = (float*)(ws);                  // 4,917,248
    float* Gl    = (float*)(ws + 4917248);        // 100,352
    float* Cb    = (float*)(ws + 5017600);        // 256
    float* part  = (float*)(ws + 5017856);        // 25,690,112
    float* maskr = (float*)(ws + 30707968);       // 6,422,528
    float* msumW = (float*)(ws + 37130496);       // 131,072 (end ~37.3MB)

    kG   <<<512, 256, 0, stream>>>(c3w, c5w, c7w, dww, dhw, accw, lnw, lnb, Gmat, Gl);
    kCb  <<<1,   64,  0, stream>>>(c3b, c5b, c7b, dww, dwb, dhw, dhb, accw, accb, Gl, Cb);
    kCw1 <<<512, 512, 0, stream>>>(x, Gmat, part);
    kLog <<<512, 512, 0, stream>>>(x, convw, convb, part, Cb, maskr, msumW);
    kVd  <<<512, 512, 0, stream>>>(x, maskr, msumW, cent, out);
}

// Round 16
// 179.529 us; speedup vs baseline: 6.2146x; 6.2146x over previous
//
#include <hip/hip_runtime.h>
#include <math.h>

#define NI 512
#define CC 512
#define KCL 64
#define HW49 49
#define CQ 25088   // 512*49
#define AP 260     // kCw1 A-tile pitch [q][n]
#define GP 68      // kCw1 G-tile pitch [q][p pad 64]
#define XQP 132    // kLog transposed quarter pitch (33 granules == 1 mod 32)

// Upsample matrix U[13][7], align_corners: even i -> 1 at i/2; odd i -> 0.5 at (i-1)/2,(i+1)/2
__device__ __forceinline__ float Uval(int i, int u) {
    if (i & 1) return (u == ((i - 1) >> 1) || u == ((i + 1) >> 1)) ? 0.5f : 0.0f;
    return (u == (i >> 1)) ? 1.0f : 0.0f;
}

// ---------------- K_G: build per-channel 49x49 operator (lnw folded in, lnb -> Gl) ----------------
__global__ __launch_bounds__(256) void kG(
    const float* __restrict__ c3w, const float* __restrict__ c5w, const float* __restrict__ c7w,
    const float* __restrict__ dww, const float* __restrict__ dhw, const float* __restrict__ accw,
    const float* __restrict__ lnw, const float* __restrict__ lnb,
    float* __restrict__ Gmat, float* __restrict__ Gl)
{
    const int c = blockIdx.x;
    const int t = threadIdx.x;
    __shared__ float dh[91], dw[91];
    __shared__ float Fh3[147], Fw3[147], Fh5[245], Fw5[245], Fh7[343], Fw7[343];
    __shared__ float wa3[9], wa5[25], wa7[49];
    __shared__ float Gtmp[2401];
    if (t < 91) dh[t] = dhw[t];
    if (t >= 128 && t < 219) dw[t - 128] = dww[t - 128];
    __syncthreads();
    for (int idx = t; idx < 147; idx += 256) {
        int oh = idx / 21, r = idx % 21, u = r / 3, dy = r % 3;
        float sh = 0.f, sw = 0.f;
        for (int i = 0; i < 13; i++) { int y = i - dy + 1; if (y >= 0 && y < 13) { float uu = Uval(i, u); sh += dh[oh * 13 + y] * uu; sw += dw[oh * 13 + y] * uu; } }
        Fh3[idx] = sh; Fw3[idx] = sw;
    }
    for (int idx = t; idx < 245; idx += 256) {
        int oh = idx / 35, r = idx % 35, u = r / 5, dy = r % 5;
        float sh = 0.f, sw = 0.f;
        for (int i = 0; i < 13; i++) { int y = i - dy + 2; if (y >= 0 && y < 13) { float uu = Uval(i, u); sh += dh[oh * 13 + y] * uu; sw += dw[oh * 13 + y] * uu; } }
        Fh5[idx] = sh; Fw5[idx] = sw;
    }
    for (int idx = t; idx < 343; idx += 256) {
        int oh = idx / 49, r = idx % 49, u = r / 7, dy = r % 7;
        float sh = 0.f, sw = 0.f;
        for (int i = 0; i < 13; i++) { int y = i - dy + 3; if (y >= 0 && y < 13) { float uu = Uval(i, u); sh += dh[oh * 13 + y] * uu; sw += dw[oh * 13 + y] * uu; } }
        Fh7[idx] = sh; Fw7[idx] = sw;
    }
    if (t < 9)               { float s = 0.f; for (int co = 0; co < 32; co++) s += accw[co]      * c3w[(size_t)(co * 512 + c) * 9  + t];        wa3[t] = s; }
    if (t >= 32 && t < 57)   { int q = t - 32; float s = 0.f; for (int co = 0; co < 32; co++) s += accw[32 + co] * c5w[(size_t)(co * 512 + c) * 25 + q]; wa5[q] = s; }
    if (t >= 64 && t < 113)  { int q = t - 64; float s = 0.f; for (int co = 0; co < 20; co++) s += accw[64 + co] * c7w[(size_t)(co * 512 + c) * 49 + q]; wa7[q] = s; }
    __syncthreads();
    for (int o = t; o < 2401; o += 256) {
        int q = o / 49, p = o % 49;
        int u = q / 7, v = q % 7, ow = p / 7, oh = p % 7;
        float acc = 0.f;
        #pragma unroll
        for (int dy = 0; dy < 3; dy++) { float fh = Fh3[(oh * 7 + u) * 3 + dy];
            #pragma unroll
            for (int dx = 0; dx < 3; dx++) acc += wa3[dy * 3 + dx] * fh * Fw3[(ow * 7 + v) * 3 + dx]; }
        #pragma unroll
        for (int dy = 0; dy < 5; dy++) { float fh = Fh5[(oh * 7 + u) * 5 + dy];
            #pragma unroll
            for (int dx = 0; dx < 5; dx++) acc += wa5[dy * 5 + dx] * fh * Fw5[(ow * 7 + v) * 5 + dx]; }
        #pragma unroll
        for (int dy = 0; dy < 7; dy++) { float fh = Fh7[(oh * 7 + u) * 7 + dy];
            #pragma unroll
            for (int dx = 0; dx < 7; dx++) acc += wa7[dy * 7 + dx] * fh * Fw7[(ow * 7 + v) * 7 + dx]; }
        Gtmp[o] = acc;
        Gmat[(size_t)c * 2401 + o] = acc * lnw[q];
    }
    __syncthreads();
    if (t < 49) {
        float s = 0.f;
        for (int q = 0; q < 49; q++) s += Gtmp[q * 49 + t] * lnb[q];
        Gl[c * 49 + t] = s;
    }
}

// ---------------- K_Cb: constant term of cw (incl. lnb fold via Gl) ----------------
__global__ void kCb(const float* __restrict__ c3b, const float* __restrict__ c5b, const float* __restrict__ c7b,
                    const float* __restrict__ dww, const float* __restrict__ dwb,
                    const float* __restrict__ dhw, const float* __restrict__ dhb,
                    const float* __restrict__ accw, const float* __restrict__ accb,
                    const float* __restrict__ Gl, float* __restrict__ Cb)
{
    __shared__ float A0s, A1s, Sdw[7], Sdh[7];
    int t = threadIdx.x;
    if (t == 0) {
        float a0 = 0.f, a1 = 0.f;
        for (int co = 0; co < 84; co++) {
            float aw = accw[co]; a0 += aw;
            float b = (co < 32) ? c3b[co] : ((co < 64) ? c5b[co - 32] : c7b[co - 64]);
            a1 += aw * b;
        }
        A0s = a0; A1s = a1;
    }
    if (t < 7)             { float s = 0.f; for (int xx = 0; xx < 13; xx++) s += dww[t * 13 + xx]; Sdw[t] = s; }
    if (t >= 8 && t < 15)  { int oh = t - 8; float s = 0.f; for (int y = 0; y < 13; y++) s += dhw[oh * 13 + y]; Sdh[oh] = s; }
    __syncthreads();
    if (t < 49) {
        int ow = t / 7, oh = t % 7;
        float g = 0.f;
        for (int c = 0; c < 512; c++) g += Gl[c * 49 + t];
        Cb[t] = A1s * Sdw[ow] * Sdh[oh] + A0s * (dwb[ow] * Sdh[oh] + dhb[oh]) + accb[0] + g;
    }
}

// ---------------- K_cw1: partial GEMM with inline LayerNorm (512 threads, 16 waves/CU) ----------------
__global__ __launch_bounds__(512) void kCw1(const float* __restrict__ x,
    const float* __restrict__ Gmat, float* __restrict__ part)
{
    __shared__ float As[49 * AP];   // [q][n]; reused as [256][49] out-stage
    __shared__ float Gs[49 * GP];   // [q][p pad 64]
    const int b = blockIdx.x;
    const int nt = b >> 8, ks = b & 255;
    const int n0 = nt * 256;
    const int t = threadIdx.x;
    const int tn = t >> 3;          // 0..63 -> rows 4*tn..4*tn+3
    const int tp = t & 7;           // p-octet
    float acc[4][8];
    #pragma unroll
    for (int j = 0; j < 4; j++)
        #pragma unroll
        for (int m = 0; m < 8; m++) acc[j][m] = 0.f;
    for (int kk = 0; kk < 2; kk++) {
        const int c = ks * 2 + kk;
        for (int i = t; i < 12544; i += 512) {
            int nr = i / 49, q = i - nr * 49;
            As[q * AP + nr] = x[(size_t)(n0 + nr) * CQ + (size_t)c * 49 + q];
        }
        for (int i = t; i < 2401; i += 512) {
            int q = i / 49, p = i - q * 49;
            Gs[q * GP + p] = Gmat[(size_t)c * 2401 + i];
        }
        for (int i = t; i < 735; i += 512) {
            int q = i / 15, pc = 49 + (i - q * 15);
            Gs[q * GP + pc] = 0.f;
        }
        __syncthreads();
        if (t < 256) {
            float s = 0.f, ss = 0.f;
            for (int q = 0; q < 49; q++) { float v = As[q * AP + t]; s += v; ss += v * v; }
            float mu = s * (1.f / 49.f);
            float var = ss * (1.f / 49.f) - mu * mu;
            float rs = 1.f / sqrtf(var + 1e-5f);
            for (int q = 0; q < 49; q++) As[q * AP + t] = (As[q * AP + t] - mu) * rs;
        }
        __syncthreads();
        for (int q = 0; q < 49; q++) {
            float4 a0 = *(const float4*)&As[q * AP + tn * 4];
            float4 g0 = *(const float4*)&Gs[q * GP + tp * 8];
            float4 g1 = *(const float4*)&Gs[q * GP + tp * 8 + 4];
            float av[4] = {a0.x, a0.y, a0.z, a0.w};
            float gv[8] = {g0.x, g0.y, g0.z, g0.w, g1.x, g1.y, g1.z, g1.w};
            #pragma unroll
            for (int j = 0; j < 4; j++)
                #pragma unroll
                for (int m = 0; m < 8; m++) acc[j][m] += av[j] * gv[m];
        }
        __syncthreads();
    }
    #pragma unroll
    for (int j = 0; j < 4; j++) {
        #pragma unroll
        for (int m = 0; m < 8; m++) {
            int p = tp * 8 + m;
            if (p < 49) As[(tn * 4 + j) * 49 + p] = acc[j][m];
        }
    }
    __syncthreads();
    {
        float* dst = part + (size_t)ks * CQ + (size_t)n0 * 49;
        for (int i = t; i < 12544; i += 512) dst[i] = As[i];
    }
}

// ---------------- K_log: cw-reduce + rn + logits + softmax -> maskr (sa*cw*rn), msum ----------------
// Double-buffered transposed x staging, s_load weights, coalesced cw-reduce.
__global__ __launch_bounds__(512) void kLog(const float* __restrict__ x,
    const float* __restrict__ convw, const float* __restrict__ convb,
    const float* __restrict__ part, const float* __restrict__ Cbg,
    float* __restrict__ maskr, float* __restrict__ msum)
{
    __shared__ float xq[2][49 * XQP];   // double-buffered quarter [49 l][132]
    __shared__ float lg[64 * 52];
    __shared__ float ps[8 * 56];
    __shared__ float rn[49], cwl[49], smax[49], sinv[49];
    __shared__ float cb[64];
    __shared__ float pmx[392], psm[392];
    const int n = blockIdx.x;
    const int t = threadIdx.x;
    const int lane = t & 63;
    const int kw = __builtin_amdgcn_readfirstlane(t >> 6);
    const float* xp = x + (size_t)n * CQ;

    // staging slot geometry (4 slots, slot 3 valid only for t<32)
    int scg[4], sl[4];
    #pragma unroll
    for (int s = 0; s < 4; s++) {
        int idx = t + s * 512;
        scg[s] = idx / 49; sl[s] = idx - scg[s] * 49;
    }
    float4 r[4];
    // issue loads for quarter 0
    #pragma unroll
    for (int s = 0; s < 4; s++) {
        if (s < 3 || t < 32) {
            const float* src = xp + (size_t)(scg[s] * 4) * 49 + sl[s];
            r[s].x = src[0]; r[s].y = src[49]; r[s].z = src[98]; r[s].w = src[147];
        }
    }
    // coalesced cw-reduce: wave kw -> ks [kw*32, kw*32+32), lane = p
    if (lane < 49) {
        const float* bp = part + (size_t)(kw * 32) * CQ + (size_t)n * 49 + lane;
        float s0 = 0.f, s1 = 0.f, s2 = 0.f, s3 = 0.f;
        for (int i = 0; i < 32; i += 4) {
            s0 += bp[(size_t)(i + 0) * CQ];
            s1 += bp[(size_t)(i + 1) * CQ];
            s2 += bp[(size_t)(i + 2) * CQ];
            s3 += bp[(size_t)(i + 3) * CQ];
        }
        psm[lane * 8 + kw] = (s0 + s1) + (s2 + s3);
    }
    if (t < 64) cb[t] = convb[t];

    float a[8] = {0.f, 0.f, 0.f, 0.f, 0.f, 0.f, 0.f, 0.f};
    float rs_part = 0.f;

    // write quarter 0, issue loads for quarter 1
    #pragma unroll
    for (int s = 0; s < 4; s++)
        if (s < 3 || t < 32) *(float4*)&xq[0][sl[s] * XQP + scg[s] * 4] = r[s];
    #pragma unroll
    for (int s = 0; s < 4; s++) {
        if (s < 3 || t < 32) {
            const float* src = xp + (size_t)(128 + scg[s] * 4) * 49 + sl[s];
            r[s].x = src[0]; r[s].y = src[49]; r[s].z = src[98]; r[s].w = src[147];
        }
    }
    __syncthreads();
    if (t < 49) {
        float s = Cbg[t];
        #pragma unroll
        for (int q = 0; q < 8; q++) s += psm[t * 8 + q];
        cwl[t] = s;
    }
    for (int qt = 0; qt < 4; qt++) {
        const float* buf = xq[qt & 1];
        if (lane < 49) {                 // rn partial: wave covers 16 c of this quarter, b128
            const float* row = &buf[lane * XQP + kw * 16];
            #pragma unroll
            for (int c4 = 0; c4 < 4; c4++) {
                float4 v = *(const float4*)(row + c4 * 4);
                rs_part += v.x * v.x + v.y * v.y + v.z * v.z + v.w * v.w;
            }
        }
        {                                // logits partial: x b128 from LDS, w via s_load
            const int lr = (lane < 49) ? lane : 48;
            const float* xrow = &buf[lr * XQP];
            const float* wb = convw + (size_t)(kw * 8) * 512 + qt * 128;
            for (int c4 = 0; c4 < 32; c4++) {
                float4 xv = *(const float4*)(xrow + c4 * 4);
                #pragma unroll
                for (int j = 0; j < 8; j++) {
                    float4 wv = *(const float4*)&wb[j * 512 + c4 * 4];
                    a[j] += wv.x * xv.x + wv.y * xv.y + wv.z * xv.z + wv.w * xv.w;
                }
            }
        }
        if (qt < 3) {
            #pragma unroll
            for (int s = 0; s < 4; s++)
                if (s < 3 || t < 32) *(float4*)&xq[(qt + 1) & 1][sl[s] * XQP + scg[s] * 4] = r[s];
            if (qt < 2) {
                #pragma unroll
                for (int s = 0; s < 4; s++) {
                    if (s < 3 || t < 32) {
                        const float* src = xp + (size_t)((qt + 2) * 128 + scg[s] * 4) * 49 + sl[s];
                        r[s].x = src[0]; r[s].y = src[49]; r[s].z = src[98]; r[s].w = src[147];
                    }
                }
            }
            __syncthreads();
        }
    }
    if (lane < 49) ps[kw * 56 + lane] = rs_part;
    __syncthreads();
    if (t < 49) {
        float s = 0.f;
        #pragma unroll
        for (int q = 0; q < 8; q++) s += ps[q * 56 + t];
        rn[t] = 1.f / fmaxf(sqrtf(s), 1e-12f);
    }
    __syncthreads();
    if (lane < 49) {
        float r0 = rn[lane];
        #pragma unroll
        for (int j = 0; j < 8; j++) lg[(kw * 8 + j) * 52 + lane] = a[j] * r0 + cb[kw * 8 + j];
    }
    __syncthreads();
    // softmax over k per l
    if (t < 392) {
        int l = t >> 3, kq = t & 7;
        float m = -3.402823466e38f;
        #pragma unroll
        for (int j = 0; j < 8; j++) m = fmaxf(m, lg[(kq * 8 + j) * 52 + l]);
        pmx[t] = m;
    }
    __syncthreads();
    if (t < 49) {
        float m = pmx[t * 8];
        #pragma unroll
        for (int q = 1; q < 8; q++) m = fmaxf(m, pmx[t * 8 + q]);
        smax[t] = m;
    }
    __syncthreads();
    if (t < 392) {
        int l = t >> 3, kq = t & 7;
        float m = smax[l], s = 0.f;
        #pragma unroll
        for (int j = 0; j < 8; j++) s += __expf(lg[(kq * 8 + j) * 52 + l] - m);
        psm[t] = s;
    }
    __syncthreads();
    if (t < 49) {
        float s = 0.f;
        #pragma unroll
        for (int q = 0; q < 8; q++) s += psm[t * 8 + q];
        sinv[t] = 1.f / s;
    }
    __syncthreads();
    if (t < 392) {
        int l = t >> 3, kq = t & 7;
        float m = smax[l], si = sinv[l] * cwl[l];
        #pragma unroll
        for (int j = 0; j < 8; j++) {
            int idx = (kq * 8 + j) * 52 + l;
            lg[idx] = __expf(lg[idx] - m) * si;    // mask = sa*cw
        }
    }
    __syncthreads();
    // msum per wave (pre-rn), then write mask*rn
    {
        float msr[8];
        #pragma unroll
        for (int j = 0; j < 8; j++) {
            float s = 0.f;
            for (int l = 0; l < 49; l++) s += lg[(kw * 8 + j) * 52 + l];
            msr[j] = s;
        }
        if (lane == 0) {
            #pragma unroll
            for (int j = 0; j < 8; j++) msum[n * 64 + kw * 8 + j] = msr[j];
        }
    }
    for (int o = t; o < 3136; o += 512) {
        int k = o / 49, l = o - k * 49;
        maskr[(size_t)n * 3136 + o] = lg[k * 52 + l] * rn[l];
    }
}

// ---------------- K_vd: VLAD aggregation + intra-norm + global norm ----------------
// NATIVE [c][49] half-tiles (straight contiguous b128 copy); lane covers c = lane + 64*ci
// (lane-stride 49 floats, odd -> conflict-free b32 reads); b128 mask broadcasts.
__global__ __launch_bounds__(512) void kVd(const float* __restrict__ x,
    const float* __restrict__ maskr, const float* __restrict__ msum,
    const float* __restrict__ cent, float* __restrict__ out)
{
    __shared__ float xh[12560];         // 256 c x 49 l native + 16 guard
    __shared__ float lg[64 * 52];       // mask (sa*cw*rn), l 49..51 padded 0
    __shared__ float ssq[64], scl[64];
    const int n = blockIdx.x;
    const int t = threadIdx.x;
    const int lane = t & 63;
    const int kw = __builtin_amdgcn_readfirstlane(t >> 6);
    const float* xp = x + (size_t)n * CQ;
    for (int i = t; i < 3136; i += 512) { int k = i / 49, l = i - k * 49; lg[k * 52 + l] = maskr[(size_t)n * 3136 + i]; }
    for (int i = t; i < 192; i += 512) { lg[(i / 3) * 52 + 49 + (i % 3)] = 0.f; }
    float msr[8];
    #pragma unroll
    for (int j = 0; j < 8; j++) msr[j] = msum[n * 64 + kw * 8 + j];
    float accA[8][4], accB[8][4];
    #pragma unroll
    for (int j = 0; j < 8; j++)
        #pragma unroll
        for (int ci = 0; ci < 4; ci++) { accA[j][ci] = 0.f; accB[j][ci] = 0.f; }
    // ---- half B (c 256..511): straight contiguous copy ----
    for (int i4 = t; i4 < 3136; i4 += 512)
        *(float4*)&xh[i4 * 4] = *(const float4*)&xp[12544 + i4 * 4];
    if (t < 16) xh[12544 + t] = 0.f;
    __syncthreads();
    for (int lq = 0; lq < 13; lq++) {
        float xr[4][4];
        #pragma unroll
        for (int ci = 0; ci < 4; ci++)
            #pragma unroll
            for (int dl = 0; dl < 4; dl++)
                xr[ci][dl] = xh[(lane + 64 * ci) * 49 + lq * 4 + dl];
        #pragma unroll
        for (int j = 0; j < 8; j++) {
            float4 mv = *(const float4*)&lg[(kw * 8 + j) * 52 + lq * 4];
            #pragma unroll
            for (int ci = 0; ci < 4; ci++)
                accB[j][ci] += mv.x * xr[ci][0] + mv.y * xr[ci][1] + mv.z * xr[ci][2] + mv.w * xr[ci][3];
        }
    }
    __syncthreads();
    // ---- half A (c 0..255) ----
    for (int i4 = t; i4 < 3136; i4 += 512)
        *(float4*)&xh[i4 * 4] = *(const float4*)&xp[i4 * 4];
    if (t < 16) xh[12544 + t] = 0.f;
    __syncthreads();
    for (int lq = 0; lq < 13; lq++) {
        float xr[4][4];
        #pragma unroll
        for (int ci = 0; ci < 4; ci++)
            #pragma unroll
            for (int dl = 0; dl < 4; dl++)
                xr[ci][dl] = xh[(lane + 64 * ci) * 49 + lq * 4 + dl];
        #pragma unroll
        for (int j = 0; j < 8; j++) {
            float4 mv = *(const float4*)&lg[(kw * 8 + j) * 52 + lq * 4];
            #pragma unroll
            for (int ci = 0; ci < 4; ci++)
                accA[j][ci] += mv.x * xr[ci][0] + mv.y * xr[ci][1] + mv.z * xr[ci][2] + mv.w * xr[ci][3];
        }
    }
    // ---- epilogue: centroid subtract, intra-norm, global norm ----
    float ssr[8];
    #pragma unroll
    for (int j = 0; j < 8; j++) {
        int k = kw * 8 + j;
        float ms = msr[j];
        float s = 0.f;
        #pragma unroll
        for (int ci = 0; ci < 4; ci++) {
            int c = lane + 64 * ci;
            float va = accA[j][ci] - cent[(size_t)k * 512 + c] * ms;
            float vb = accB[j][ci] - cent[(size_t)k * 512 + 256 + c] * ms;
            accA[j][ci] = va; accB[j][ci] = vb;
            s += va * va + vb * vb;
        }
        ssr[j] = s;
    }
    #pragma unroll
    for (int j = 0; j < 8; j++)
        for (int off = 32; off >= 1; off >>= 1) ssr[j] += __shfl_xor(ssr[j], off, 64);
    if (lane == 0) {
        #pragma unroll
        for (int j = 0; j < 8; j++) ssq[kw * 8 + j] = ssr[j];
    }
    __syncthreads();
    if (t < 64) {
        float nrm = sqrtf(ssq[t]);
        float inv = 1.f / fmaxf(nrm, 1e-12f);
        float sk = nrm * inv;
        float g = sk * sk;
        #pragma unroll
        for (int off = 32; off >= 1; off >>= 1) g += __shfl_xor(g, off, 64);
        scl[t] = inv * (1.f / fmaxf(sqrtf(g), 1e-12f));
    }
    __syncthreads();
    #pragma unroll
    for (int j = 0; j < 8; j++) {
        int k = kw * 8 + j;
        float s2 = scl[k];
        #pragma unroll
        for (int ci = 0; ci < 4; ci++) {
            int c = lane + 64 * ci;
            out[(size_t)n * 32768 + (size_t)k * 512 + c] = accA[j][ci] * s2;
            out[(size_t)n * 32768 + (size_t)k * 512 + 256 + c] = accB[j][ci] * s2;
        }
    }
}

extern "C" void kernel_launch(void* const* d_in, const int* in_sizes, int n_in,
                              void* d_out, int out_size, void* d_ws, size_t ws_size,
                              hipStream_t stream)
{
    const float* x     = (const float*)d_in[0];
    const float* cent  = (const float*)d_in[1];
    const float* convw = (const float*)d_in[2];
    const float* convb = (const float*)d_in[3];
    const float* lnw   = (const float*)d_in[4];
    const float* lnb   = (const float*)d_in[5];
    const float* c3w   = (const float*)d_in[6];
    const float* c3b   = (const float*)d_in[7];
    const float* c5w   = (const float*)d_in[8];
    const float* c5b   = (const float*)d_in[9];
    const float* c7w   = (const float*)d_in[10];
    const float* c7b   = (const float*)d_in[11];
    const float* dww   = (const float*)d_in[12];
    const float* dwb   = (const float*)d_in[13];
    const float* dhw   = (const float*)d_in[14];
    const float* dhb   = (const float*)d_in[15];
    const float* accw  = (const float*)d_in[16];
    const float* accb  = (const float*)d_in[17];
    float* out = (float*)d_out;

    char* ws = (char*)d_ws;
    float* Gmat  = (float*)(ws);                  // 4,917,248
    float* Gl    = (float*)(ws + 4917248);        // 100,352
    float* Cb    = (float*)(ws + 5017600);        // 256
    float* part  = (float*)(ws + 5017856);        // 25,690,112
    float* maskr = (float*)(ws + 30707968);       // 6,422,528
    float* msumW = (float*)(ws + 37130496);       // 131,072 (end ~37.3MB)

    kG   <<<512, 256, 0, stream>>>(c3w, c5w, c7w, dww, dhw, accw, lnw, lnb, Gmat, Gl);
    kCb  <<<1,   64,  0, stream>>>(c3b, c5b, c7b, dww, dwb, dhw, dhb, accw, accb, Gl, Cb);
    kCw1 <<<512, 512, 0, stream>>>(x, Gmat, part);
    kLog <<<512, 512, 0, stream>>>(x, convw, convb, part, Cb, maskr, msumW);
    kVd  <<<512, 512, 0, stream>>>(x, maskr, msumW, cent, out);
}